// Round 8
// baseline (127.903 us; speedup 1.0000x reference)
//
#include <hip/hip_runtime.h>

// Fused iterated 3x3 median blur (edge-replicate), up to 9 iterations.
//
// R8 = the best-measured structure (R0/R1: 256 threads, 64x64 output tile,
// 82x82 LDS halo tile, per-lane 5x5 register patch, in-place update) with
// the two lessons from the R3-R7 wave-autonomous arc applied:
//  (a) template-unrolled k-loop (switch over T=1..9). Every runtime-k
//      variant measured VGPR_Count 56-68 = compiler demotes the patch
//      array to scratch; only full unroll kept it resident (R6: VGPR 84).
//  (b) __launch_bounds__(256,5): VGPR cap 102 -> 5 blocks/CU (LDS 26.9KB
//      allows it) = 20 waves/CU instead of 16.
// Everything else (geometry, halo load, ring exchange, pad fixups, store)
// is byte-identical to the R1 kernel that passed with absmax 0.0.
//
// Structure recap: each thread owns a contiguous 5x5 patch of compute
// region [1,80]^2 kept in registers across iterations. Per iteration only
// the 24-cell halo ring is read from LDS and the 16-cell patch perimeter
// written back (interior never read by others). Final iteration publishes
// all 25 for the vectorized store phase. Image-edge replicate pads are
// register fixups in pad-owning threads (row fix then col fix -> corners
// exact); perimeter writes then carry pad values to LDS.

#define TD 82
#define OW 64
#define RAD 9
#define NT 256

static __device__ __forceinline__ float min3f(float a, float b, float c) { return fminf(fminf(a, b), c); }
static __device__ __forceinline__ float max3f(float a, float b, float c) { return fmaxf(fmaxf(a, b), c); }
static __device__ __forceinline__ float med3f(float a, float b, float c) { return __builtin_amdgcn_fmed3f(a, b, c); }

template<int T>
static __device__ __forceinline__ void run_iters(
    float* __restrict__ buf, int ub, int vb,
    bool padTop, bool padBot, bool padLft, bool padRgt)
{
    // preload own 5x5 patch (state 0) into registers
    float stage[25];
    #pragma unroll
    for (int i = 0; i < 5; ++i)
        #pragma unroll
        for (int j = 0; j < 5; ++j)
            stage[i * 5 + j] = buf[(ub + i) * TD + vb + j];

    #pragma unroll
    for (int k = 0; k < T; ++k) {
        float A[7], Br[7], C[7];
        // window row ub-1: all 7 from LDS (neighbor ring)
        {
            const float* p = &buf[(ub - 1) * TD + (vb - 1)];
            #pragma unroll
            for (int j = 0; j < 7; ++j) A[j] = p[j];
        }
        // window row ub: edges from LDS, middle from stage row 0
        Br[0] = buf[ub * TD + (vb - 1)];
        #pragma unroll
        for (int j = 0; j < 5; ++j) Br[1 + j] = stage[j];
        Br[6] = buf[ub * TD + (vb + 5)];

        #pragma unroll
        for (int i = 0; i < 5; ++i) {
            if (i < 4) {                // rows ub+1..ub+4: edges LDS, mid regs
                C[0] = buf[(ub + 1 + i) * TD + (vb - 1)];
                #pragma unroll
                for (int j = 0; j < 5; ++j) C[1 + j] = stage[(i + 1) * 5 + j];
                C[6] = buf[(ub + 1 + i) * TD + (vb + 5)];
            } else {                    // row ub+5: all 7 from LDS
                const float* p = &buf[(ub + 5) * TD + (vb - 1)];
                #pragma unroll
                for (int j = 0; j < 7; ++j) C[j] = p[j];
            }
            float lo[7], mi[7], hi[7];
            #pragma unroll
            for (int j = 0; j < 7; ++j) {
                lo[j] = min3f(A[j], Br[j], C[j]);
                mi[j] = med3f(A[j], Br[j], C[j]);
                hi[j] = max3f(A[j], Br[j], C[j]);
            }
            // in-place: old row i is held in Br; row i+1 already in C
            #pragma unroll
            for (int j = 0; j < 5; ++j)
                stage[i * 5 + j] = med3f(max3f(lo[j], lo[j+1], lo[j+2]),
                                         med3f(mi[j], mi[j+1], mi[j+2]),
                                         min3f(hi[j], hi[j+1], hi[j+2]));
            #pragma unroll
            for (int j = 0; j < 7; ++j) { A[j] = Br[j]; Br[j] = C[j]; }
        }

        // register pad fixups (row fix first, then col fix -> corners exact)
        if (padTop) {                   // pad row 8 (i=2) <- new row 9 (i=3)
            #pragma unroll
            for (int j = 0; j < 5; ++j) stage[10 + j] = stage[15 + j];
        }
        if (padBot) {                   // pad row 73 (i=2) <- new row 72 (i=1)
            #pragma unroll
            for (int j = 0; j < 5; ++j) stage[10 + j] = stage[5 + j];
        }
        if (padLft) {                   // pad col 8 (j=2) <- new col 9 (j=3)
            #pragma unroll
            for (int i = 0; i < 5; ++i) stage[i * 5 + 2] = stage[i * 5 + 3];
        }
        if (padRgt) {                   // pad col 73 (j=2) <- new col 72 (j=1)
            #pragma unroll
            for (int i = 0; i < 5; ++i) stage[i * 5 + 2] = stage[i * 5 + 1];
        }

        __syncthreads();                // all ring reads of state k done (WAR)

        if (k == T - 1) {               // final (static): write all 25
            #pragma unroll
            for (int i = 0; i < 5; ++i)
                #pragma unroll
                for (int j = 0; j < 5; ++j)
                    buf[(ub + i) * TD + vb + j] = stage[i * 5 + j];
        } else {                        // write the 16-cell patch perimeter
            #pragma unroll
            for (int j = 0; j < 5; ++j) buf[ub * TD + vb + j]       = stage[j];
            #pragma unroll
            for (int j = 0; j < 5; ++j) buf[(ub + 4) * TD + vb + j] = stage[20 + j];
            #pragma unroll
            for (int i = 1; i < 4; ++i) {
                buf[(ub + i) * TD + vb]     = stage[i * 5];
                buf[(ub + i) * TD + vb + 4] = stage[i * 5 + 4];
            }
        }

        __syncthreads();                // new ring visible (RAW)
    }
}

__global__ __launch_bounds__(NT, 5) void median_fused_kernel(
    const float* __restrict__ src, float* __restrict__ dst,
    const int* __restrict__ t)
{
    __shared__ float buf[TD * TD];

    const int b   = blockIdx.y;
    const int y0  = (blockIdx.x >> 3) * OW;   // 8x8 tiles of 64
    const int x0  = (blockIdx.x & 7) * OW;
    const int tid = threadIdx.x;
    const float* img  = src + (b << 18);
    float*       outb = dst + (b << 18);

    int T = t[b];
    T = min(max(T, 0), 9);

    const int sr = tid >> 4;            // store: 16 row groups x 4
    const int sc = (tid & 15) << 2;     // store: 16 x float4

    if (T == 0) {                       // straight vector copy, no LDS
        #pragma unroll
        for (int rr = 0; rr < 4; ++rr) {
            int gy = y0 + sr + rr * 16;
            *(float4*)&outb[(gy << 9) + x0 + sc] =
                *(const float4*)&img[(gy << 9) + x0 + sc];
        }
        return;
    }

    // ---- load 82x82 halo tile, clamped (= replicate-padded image) ----
    for (int i = tid; i < TD * TD; i += NT) {
        int r = i / TD, c = i - r * TD;
        int gy = min(max(y0 - RAD + r, 0), 511);
        int gx = min(max(x0 - RAD + c, 0), 511);
        buf[i] = img[(gy << 9) + gx];
    }

    const bool topE = (y0 == 0), botE = (y0 == 512 - OW);
    const bool lftE = (x0 == 0), rgtE = (x0 == 512 - OW);

    const int ptx = tid & 15;           // 16 col groups x 5
    const int pty = tid >> 4;           // 16 row groups x 5
    const int ub  = 1 + 5 * pty;        // patch rows [ub, ub+4]
    const int vb  = 1 + 5 * ptx;        // patch cols [vb, vb+4]

    // pad-owning threads: image row 0 = tile row 9 = pty==1 patch-row i=3
    // (pad row 8 = i=2); image row 511 = tile row 72 = pty==14 i=1 (pad 73
    // = i=2). Columns symmetric.
    const bool padTop = topE && (pty == 1);
    const bool padBot = botE && (pty == 14);
    const bool padLft = lftE && (ptx == 1);
    const bool padRgt = rgtE && (ptx == 14);

    __syncthreads();

    switch (T) {
        case 1: run_iters<1>(buf, ub, vb, padTop, padBot, padLft, padRgt); break;
        case 2: run_iters<2>(buf, ub, vb, padTop, padBot, padLft, padRgt); break;
        case 3: run_iters<3>(buf, ub, vb, padTop, padBot, padLft, padRgt); break;
        case 4: run_iters<4>(buf, ub, vb, padTop, padBot, padLft, padRgt); break;
        case 5: run_iters<5>(buf, ub, vb, padTop, padBot, padLft, padRgt); break;
        case 6: run_iters<6>(buf, ub, vb, padTop, padBot, padLft, padRgt); break;
        case 7: run_iters<7>(buf, ub, vb, padTop, padBot, padLft, padRgt); break;
        case 8: run_iters<8>(buf, ub, vb, padTop, padBot, padLft, padRgt); break;
        default: run_iters<9>(buf, ub, vb, padTop, padBot, padLft, padRgt); break;
    }

    // ---- store 64x64 output tile, float4 global stores ----
    #pragma unroll
    for (int rr = 0; rr < 4; ++rr) {
        int row = sr + rr * 16;
        const float* s = &buf[(row + RAD) * TD + RAD + sc];
        float4 v = { s[0], s[1], s[2], s[3] };
        *(float4*)&outb[((y0 + row) << 9) + x0 + sc] = v;
    }
}

extern "C" void kernel_launch(void* const* d_in, const int* in_sizes, int n_in,
                              void* d_out, int out_size, void* d_ws, size_t ws_size,
                              hipStream_t stream) {
    const float* x   = (const float*)d_in[0];
    const int*   t   = (const int*)d_in[1];
    float*       out = (float*)d_out;

    dim3 block(NT);
    dim3 grid(64, 32);   // 8x8 full tiles x 32 batches
    median_fused_kernel<<<grid, block, 0, stream>>>(x, out, t);
}

// Round 9
// 111.357 us; speedup vs baseline: 1.1486x; 1.1486x over previous
//
#include <hip/hip_runtime.h>

// Fused iterated 3x3 median blur (edge-replicate), up to 9 iterations.
//
// R9: occupancy-retuned ring/patch structure + consumer-side pad synthesis.
//  - R8 lesson: template unroll => total scratch demotion (VGPR 48, 51MB of
//    spill writes to HBM). Runtime k-loop with MILD scratch is the proven
//    neutral config (R5/R6/R7: resident-vs-scratch made no difference).
//  - R1 (38us) is latency-bound (proxy counters: VALU 21%, DS ~25%, HBM 25%,
//    occ 31%). Lever = concurrency: patch 4x4, output 48x48, tile 66x66 =
//    17.4KB LDS -> 8 blocks/CU (32 waves = HW max) vs R1's 4-6.
//  - Ring: 20 reads + 12 writes per thread-iter, same-base const offsets
//    (DS combiner -> read2/write2).
//  - Pads: NOT maintained. At image edges the replicate value equals the
//    reader's own adjacent data: subTop -> A=Br; subBot -> C=Br (last row);
//    subLft/subRgt -> window edge cell = own edge cell. Validity [k,65-k],
//    k=9 -> rows/cols 9..56 = exactly the 48x48 output tile.
// Grid: 11x11 tiles of 48 (528>=512; edge tiles guarded) x 32 batches.

#define TD  66
#define OW  48
#define RAD 9
#define NT  256

static __device__ __forceinline__ float min3f(float a, float b, float c) { return fminf(fminf(a, b), c); }
static __device__ __forceinline__ float max3f(float a, float b, float c) { return fmaxf(fmaxf(a, b), c); }
static __device__ __forceinline__ float med3f(float a, float b, float c) { return __builtin_amdgcn_fmed3f(a, b, c); }

__global__ __launch_bounds__(NT, 8) void median_fused_kernel(
    const float* __restrict__ src, float* __restrict__ dst,
    const int* __restrict__ t)
{
    __shared__ float buf[TD * TD];    // 66x66 = 17424 B

    const int b   = blockIdx.y;
    const int ty  = blockIdx.x / 11;
    const int tx  = blockIdx.x - ty * 11;
    const int y0  = ty * OW;
    const int x0  = tx * OW;
    const int tid = threadIdx.x;
    const float* img  = src + (b << 18);
    float*       outb = dst + (b << 18);

    int T = t[b];
    T = min(max(T, 0), 9);

    if (T == 0) {                       // straight vector copy, no LDS
        for (int idx = tid; idx < 576; idx += NT) {   // 48 rows x 12 float4
            int row = idx / 12, c4 = idx - row * 12;
            int gy = y0 + row, gx = x0 + (c4 << 2);
            if (gy < 512 && gx < 512)
                *(float4*)&outb[(gy << 9) + gx] =
                    *(const float4*)&img[(gy << 9) + gx];
        }
        return;
    }

    // ---- load 66x66 halo tile, clamped (= replicate-padded image) ----
    for (int i = tid; i < TD * TD; i += NT) {
        int r = i / TD, c = i - r * TD;
        int gy = min(max(y0 - RAD + r, 0), 511);
        int gx = min(max(x0 - RAD + c, 0), 511);
        buf[i] = img[(gy << 9) + gx];
    }

    // lane -> 4x4 patch of compute region [1,64]^2 (static ring rows/cols 0,65)
    const int ptx = tid & 15;           // 16 col groups x 4
    const int pty = tid >> 4;           // 16 row groups x 4
    const int ub  = 1 + (pty << 2);     // patch rows [ub, ub+3]
    const int vb  = 1 + (ptx << 2);     // patch cols [vb, vb+3]

    // consumer-side pad synthesis (tile row r <-> image row y0-9+r):
    //  top: image row 0 = tile row 9 = pty==2 row 0; its A-row (row 8) is the
    //       pad = replicate of row 9 = own Br          -> subTop: A = Br
    //  bot (y0==480): image row 511 = tile row 40 = pty==9 row 3; its last
    //       C-row (row 41) = replicate of row 40 = Br  -> subBot: C = Br
    //  lft: image col 0 = col 9 = ptx==2 col 0; window col 8 = own col 0
    //  rgt (x0==480): image col 511 = col 40 = ptx==9 col 3; window col 41
    //       = own col 3
    const bool subTop = (y0 == 0)   && (pty == 2);
    const bool subBot = (y0 == 480) && (pty == 9);
    const bool subLft = (x0 == 0)   && (ptx == 2);
    const bool subRgt = (x0 == 480) && (ptx == 9);

    __syncthreads();

    // preload own 4x4 patch (state 0) into registers
    float stage[16];
    #pragma unroll
    for (int i = 0; i < 4; ++i)
        #pragma unroll
        for (int j = 0; j < 4; ++j)
            stage[i * 4 + j] = buf[(ub + i) * TD + vb + j];

    for (int k = 0; k < T; ++k) {
        float A[6], Br[6], C[6];

        // window row ub: middle from stage row 0, sides from LDS or own edge
        Br[1] = stage[0]; Br[2] = stage[1]; Br[3] = stage[2]; Br[4] = stage[3];
        {
            const float* p = &buf[ub * TD + vb - 1];
            Br[0] = subLft ? stage[0] : p[0];
            Br[5] = subRgt ? stage[3] : p[5];
        }
        // window row ub-1: neighbor ring, or replicate (= Br) at top edge
        if (subTop) {
            #pragma unroll
            for (int j = 0; j < 6; ++j) A[j] = Br[j];
        } else {
            const float* p = &buf[(ub - 1) * TD + (vb - 1)];
            #pragma unroll
            for (int j = 0; j < 6; ++j) A[j] = p[j];
            if (subLft) A[0] = A[1];
            if (subRgt) A[5] = A[4];
        }

        #pragma unroll
        for (int i = 0; i < 4; ++i) {
            if (i < 3) {                // rows ub+1..ub+3: sides LDS, mid regs
                const float* p = &buf[(ub + 1 + i) * TD + (vb - 1)];
                C[1] = stage[(i + 1) * 4 + 0];
                C[2] = stage[(i + 1) * 4 + 1];
                C[3] = stage[(i + 1) * 4 + 2];
                C[4] = stage[(i + 1) * 4 + 3];
                C[0] = subLft ? C[1] : p[0];
                C[5] = subRgt ? C[4] : p[5];
            } else if (subBot) {        // row ub+4 = pad = replicate of Br
                #pragma unroll
                for (int j = 0; j < 6; ++j) C[j] = Br[j];
            } else {                    // row ub+4: all 6 from LDS
                const float* p = &buf[(ub + 4) * TD + (vb - 1)];
                #pragma unroll
                for (int j = 0; j < 6; ++j) C[j] = p[j];
                if (subLft) C[0] = C[1];
                if (subRgt) C[5] = C[4];
            }
            float lo[6], mi[6], hi[6];
            #pragma unroll
            for (int j = 0; j < 6; ++j) {
                lo[j] = min3f(A[j], Br[j], C[j]);
                mi[j] = med3f(A[j], Br[j], C[j]);
                hi[j] = max3f(A[j], Br[j], C[j]);
            }
            // in-place: old row i survives in Br; row i+1 already read into C
            #pragma unroll
            for (int j = 0; j < 4; ++j)
                stage[i * 4 + j] = med3f(max3f(lo[j], lo[j+1], lo[j+2]),
                                         med3f(mi[j], mi[j+1], mi[j+2]),
                                         min3f(hi[j], hi[j+1], hi[j+2]));
            #pragma unroll
            for (int j = 0; j < 6; ++j) { A[j] = Br[j]; Br[j] = C[j]; }
        }

        __syncthreads();                // all ring reads of state k done (WAR)

        // publish the 12-cell patch perimeter (same-base pairs -> write2)
        buf[ub * TD + vb + 0]       = stage[0];
        buf[ub * TD + vb + 1]       = stage[1];
        buf[ub * TD + vb + 2]       = stage[2];
        buf[ub * TD + vb + 3]       = stage[3];
        buf[(ub + 3) * TD + vb + 0] = stage[12];
        buf[(ub + 3) * TD + vb + 1] = stage[13];
        buf[(ub + 3) * TD + vb + 2] = stage[14];
        buf[(ub + 3) * TD + vb + 3] = stage[15];
        buf[(ub + 1) * TD + vb + 0] = stage[4];
        buf[(ub + 1) * TD + vb + 3] = stage[7];
        buf[(ub + 2) * TD + vb + 0] = stage[8];
        buf[(ub + 2) * TD + vb + 3] = stage[11];

        __syncthreads();                // new ring visible (RAW)
    }

    // publish the 4 interior cells for the store phase
    buf[(ub + 1) * TD + vb + 1] = stage[5];
    buf[(ub + 1) * TD + vb + 2] = stage[6];
    buf[(ub + 2) * TD + vb + 1] = stage[9];
    buf[(ub + 2) * TD + vb + 2] = stage[10];
    __syncthreads();

    // ---- store 48x48 output tile (tile rows/cols 9..56), float4 global ----
    for (int idx = tid; idx < 576; idx += NT) {       // 48 rows x 12 float4
        int row = idx / 12, c4 = idx - row * 12;
        int gy = y0 + row, gx = x0 + (c4 << 2);
        if (gy < 512 && gx < 512) {
            const float* s = &buf[(RAD + row) * TD + RAD + (c4 << 2)];
            float4 v = { s[0], s[1], s[2], s[3] };
            *(float4*)&outb[(gy << 9) + gx] = v;
        }
    }
}

extern "C" void kernel_launch(void* const* d_in, const int* in_sizes, int n_in,
                              void* d_out, int out_size, void* d_ws, size_t ws_size,
                              hipStream_t stream) {
    const float* x   = (const float*)d_in[0];
    const int*   t   = (const int*)d_in[1];
    float*       out = (float*)d_out;

    dim3 block(NT);
    dim3 grid(121, 32);   // 11x11 tiles of 48 x 32 batches
    median_fused_kernel<<<grid, block, 0, stream>>>(x, out, t);
}